// Round 1
// baseline (6494.433 us; speedup 1.0000x reference)
//
#include <hip/hip_runtime.h>

#define NN 100000
#define CC 128
#define EE 1600000
#define GG 1024
#define LL 5

__device__ __forceinline__ float sigmoidf_(float x) { return 1.0f / (1.0f + __expf(-x)); }
__device__ __forceinline__ float tanhf_(float x) {
  float xx = fminf(15.0f, fmaxf(-15.0f, x));
  float t = __expf(-2.0f * xx);
  return (1.0f - t) / (1.0f + t);
}

// h0 = x @ W_emb + b_emb   (x: [N,32], W_emb: [32,128])
__global__ __launch_bounds__(128) void embed_kernel(
    const float* __restrict__ x, const float* __restrict__ W_emb,
    const float* __restrict__ b_emb, float* __restrict__ h)
{
  const int node = blockIdx.x;
  const int c = threadIdx.x;
  float acc = b_emb[c];
  #pragma unroll
  for (int k = 0; k < 32; ++k)
    acc = fmaf(x[node * 32 + k], W_emb[k * CC + c], acc);
  h[(size_t)node * CC + c] = acc;
}

// m = h @ Wl   (Wl row-major [k][c]); 32 nodes per block, 128 threads
__global__ __launch_bounds__(128) void gemm_m_kernel(
    const float* __restrict__ h, const float* __restrict__ W,
    float* __restrict__ m)
{
  __shared__ float As[32][133];  // [node][k], odd-ish pad for conflict-free reads
  __shared__ float Bs[32][132];  // [k][c] chunk, pad keeps float4 alignment
  const int nb = blockIdx.x * 32;
  const int tid = threadIdx.x;
  const int tx = tid & 15, ty = tid >> 4;
  const int j0 = tx * 8, n0 = ty * 4;

  {
    const int nr = tid >> 2, kc = (tid & 3) * 32;
    const float* src = h + (size_t)(nb + nr) * CC + kc;
    #pragma unroll
    for (int i = 0; i < 32; i += 4) {
      float4 v = *(const float4*)(src + i);
      As[nr][kc + i] = v.x; As[nr][kc + i + 1] = v.y;
      As[nr][kc + i + 2] = v.z; As[nr][kc + i + 3] = v.w;
    }
  }

  float acc[4][8];
  #pragma unroll
  for (int i = 0; i < 4; ++i)
    #pragma unroll
    for (int j = 0; j < 8; ++j) acc[i][j] = 0.0f;

  for (int kt = 0; kt < 4; ++kt) {
    __syncthreads();
    {
      const int kr = tid >> 2, cc0 = (tid & 3) * 32;
      const float* src = W + (size_t)(kt * 32 + kr) * CC + cc0;
      #pragma unroll
      for (int i = 0; i < 32; i += 4)
        *(float4*)&Bs[kr][cc0 + i] = *(const float4*)(src + i);
    }
    __syncthreads();
    #pragma unroll
    for (int k = 0; k < 32; ++k) {
      float a[4];
      #pragma unroll
      for (int i = 0; i < 4; ++i) a[i] = As[n0 + i][kt * 32 + k];
      float4 b0 = *(const float4*)&Bs[k][j0];
      float4 b1 = *(const float4*)&Bs[k][j0 + 4];
      float bv[8] = {b0.x, b0.y, b0.z, b0.w, b1.x, b1.y, b1.z, b1.w};
      #pragma unroll
      for (int i = 0; i < 4; ++i)
        #pragma unroll
        for (int j = 0; j < 8; ++j)
          acc[i][j] = fmaf(a[i], bv[j], acc[i][j]);
    }
  }

  #pragma unroll
  for (int i = 0; i < 4; ++i) {
    float* dst = m + (size_t)(nb + n0 + i) * CC + j0;
    *(float4*)dst       = make_float4(acc[i][0], acc[i][1], acc[i][2], acc[i][3]);
    *(float4*)(dst + 4) = make_float4(acc[i][4], acc[i][5], acc[i][6], acc[i][7]);
  }
}

// agg[dst] += m[src] * w    (one wave per edge iteration; lane = channel, 2 per lane)
__global__ __launch_bounds__(256) void scatter_kernel(
    const float* __restrict__ m, const int* __restrict__ eidx,
    const float* __restrict__ ew, float* __restrict__ agg)
{
  const int lane = threadIdx.x & 63;
  const int wid = (blockIdx.x * blockDim.x + threadIdx.x) >> 6;
  const int nw = (gridDim.x * blockDim.x) >> 6;
  for (int e = wid; e < EE; e += nw) {
    const int s = eidx[e];
    const int d = eidx[EE + e];
    const float w = ew[e];
    const float v0 = m[(size_t)s * CC + lane] * w;
    const float v1 = m[(size_t)s * CC + 64 + lane] * w;
    atomicAdd(&agg[(size_t)d * CC + lane], v0);
    atomicAdd(&agg[(size_t)d * CC + 64 + lane], v1);
  }
}

// one gate-chunk matmul: acci = As @ W_ih[goff:goff+128]ᵀ, acch = Hs @ W_hh[...]ᵀ
__device__ __forceinline__ void gate_mm(
    const float (*As)[133], const float (*Hs)[133],
    float (*Wi)[132], float (*Wh)[132],
    const float* __restrict__ W_ih, const float* __restrict__ W_hh,
    int goff, int j0, int n0, int tid,
    float acci[4][8], float acch[4][8])
{
  #pragma unroll
  for (int i = 0; i < 4; ++i)
    #pragma unroll
    for (int j = 0; j < 8; ++j) { acci[i][j] = 0.0f; acch[i][j] = 0.0f; }

  for (int kt = 0; kt < 8; ++kt) {
    __syncthreads();
    {
      // thread = output row j (0..127); W rows contiguous in k -> transpose-store
      const float* si = W_ih + (size_t)(goff + tid) * CC + kt * 16;
      const float* sh = W_hh + (size_t)(goff + tid) * CC + kt * 16;
      #pragma unroll
      for (int i = 0; i < 16; i += 4) {
        float4 vi = *(const float4*)(si + i);
        Wi[i][tid] = vi.x; Wi[i + 1][tid] = vi.y; Wi[i + 2][tid] = vi.z; Wi[i + 3][tid] = vi.w;
        float4 vh = *(const float4*)(sh + i);
        Wh[i][tid] = vh.x; Wh[i + 1][tid] = vh.y; Wh[i + 2][tid] = vh.z; Wh[i + 3][tid] = vh.w;
      }
    }
    __syncthreads();
    #pragma unroll
    for (int k = 0; k < 16; ++k) {
      float a[4], hv[4];
      #pragma unroll
      for (int i = 0; i < 4; ++i) {
        a[i]  = As[n0 + i][kt * 16 + k];
        hv[i] = Hs[n0 + i][kt * 16 + k];
      }
      float4 wi0 = *(const float4*)&Wi[k][j0];
      float4 wi1 = *(const float4*)&Wi[k][j0 + 4];
      float4 wh0 = *(const float4*)&Wh[k][j0];
      float4 wh1 = *(const float4*)&Wh[k][j0 + 4];
      float wiv[8] = {wi0.x, wi0.y, wi0.z, wi0.w, wi1.x, wi1.y, wi1.z, wi1.w};
      float whv[8] = {wh0.x, wh0.y, wh0.z, wh0.w, wh1.x, wh1.y, wh1.z, wh1.w};
      #pragma unroll
      for (int i = 0; i < 4; ++i)
        #pragma unroll
        for (int j = 0; j < 8; ++j) {
          acci[i][j] = fmaf(a[i],  wiv[j], acci[i][j]);
          acch[i][j] = fmaf(hv[i], whv[j], acch[i][j]);
        }
    }
  }
}

// fused GRU cell: h = GRU(agg, h); in-place safe (per-node elementwise after dots)
__global__ __launch_bounds__(128) void gru_kernel(
    const float* __restrict__ agg, float* __restrict__ h,
    const float* __restrict__ W_ih, const float* __restrict__ W_hh,
    const float* __restrict__ b_ih, const float* __restrict__ b_hh)
{
  __shared__ float As[32][133];
  __shared__ float Hs[32][133];
  __shared__ float Wi[16][132];
  __shared__ float Wh[16][132];
  const int nb = blockIdx.x * 32;
  const int tid = threadIdx.x;
  const int tx = tid & 15, ty = tid >> 4;
  const int j0 = tx * 8, n0 = ty * 4;

  {
    const int nr = tid >> 2, kc = (tid & 3) * 32;
    const float* sa = agg + (size_t)(nb + nr) * CC + kc;
    const float* sh = h + (size_t)(nb + nr) * CC + kc;
    #pragma unroll
    for (int i = 0; i < 32; i += 4) {
      float4 va = *(const float4*)(sa + i);
      As[nr][kc + i] = va.x; As[nr][kc + i + 1] = va.y;
      As[nr][kc + i + 2] = va.z; As[nr][kc + i + 3] = va.w;
      float4 vh = *(const float4*)(sh + i);
      Hs[nr][kc + i] = vh.x; Hs[nr][kc + i + 1] = vh.y;
      Hs[nr][kc + i + 2] = vh.z; Hs[nr][kc + i + 3] = vh.w;
    }
  }

  float acci[4][8], acch[4][8];
  float r_[4][8], nn_[4][8];

  // r gate (rows 0..127): only the sum gi+gh is needed
  gate_mm(As, Hs, Wi, Wh, W_ih, W_hh, 0, j0, n0, tid, acci, acch);
  #pragma unroll
  for (int i = 0; i < 4; ++i)
    #pragma unroll
    for (int j = 0; j < 8; ++j)
      r_[i][j] = sigmoidf_(acci[i][j] + acch[i][j] + b_ih[j0 + j] + b_hh[j0 + j]);

  // n gate (rows 256..383): needs i_n and h_n separately (r * h_n)
  gate_mm(As, Hs, Wi, Wh, W_ih, W_hh, 256, j0, n0, tid, acci, acch);
  #pragma unroll
  for (int i = 0; i < 4; ++i)
    #pragma unroll
    for (int j = 0; j < 8; ++j)
      nn_[i][j] = tanhf_(acci[i][j] + b_ih[256 + j0 + j] +
                         r_[i][j] * (acch[i][j] + b_hh[256 + j0 + j]));

  // z gate (rows 128..255) + final blend + store
  gate_mm(As, Hs, Wi, Wh, W_ih, W_hh, 128, j0, n0, tid, acci, acch);
  #pragma unroll
  for (int i = 0; i < 4; ++i) {
    float hn[8];
    #pragma unroll
    for (int j = 0; j < 8; ++j) {
      float z = sigmoidf_(acci[i][j] + acch[i][j] + b_ih[128 + j0 + j] + b_hh[128 + j0 + j]);
      hn[j] = (1.0f - z) * nn_[i][j] + z * Hs[n0 + i][j0 + j];
    }
    float* dst = h + (size_t)(nb + n0 + i) * CC + j0;
    *(float4*)dst       = make_float4(hn[0], hn[1], hn[2], hn[3]);
    *(float4*)(dst + 4) = make_float4(hn[4], hn[5], hn[6], hn[7]);
  }
}

// out[batch[n]] += h[n] . W_prop + b_prop   (wave per node)
__global__ __launch_bounds__(256) void prop_kernel(
    const float* __restrict__ h, const int* __restrict__ batch,
    const float* __restrict__ Wp, const float* __restrict__ bp,
    float* __restrict__ out)
{
  const int lane = threadIdx.x & 63;
  const int wid = (blockIdx.x * blockDim.x + threadIdx.x) >> 6;
  const int nw = (gridDim.x * blockDim.x) >> 6;
  for (int node = wid; node < NN; node += nw) {
    float v = h[(size_t)node * CC + lane] * Wp[lane]
            + h[(size_t)node * CC + 64 + lane] * Wp[64 + lane];
    #pragma unroll
    for (int off = 32; off > 0; off >>= 1) v += __shfl_down(v, off, 64);
    if (lane == 0) atomicAdd(&out[batch[node]], v + bp[0]);
  }
}

extern "C" void kernel_launch(void* const* d_in, const int* in_sizes, int n_in,
                              void* d_out, int out_size, void* d_ws, size_t ws_size,
                              hipStream_t stream)
{
  const float* x      = (const float*)d_in[0];
  const int*   eidx   = (const int*)d_in[1];
  const float* ew     = (const float*)d_in[2];
  const int*   batch  = (const int*)d_in[3];
  const float* W_emb  = (const float*)d_in[4];
  const float* b_emb  = (const float*)d_in[5];
  const float* W      = (const float*)d_in[6];
  const float* W_ih   = (const float*)d_in[7];
  const float* W_hh   = (const float*)d_in[8];
  const float* b_ih   = (const float*)d_in[9];
  const float* b_hh   = (const float*)d_in[10];
  const float* W_prop = (const float*)d_in[11];
  const float* b_prop = (const float*)d_in[12];
  float* out = (float*)d_out;

  float* h   = (float*)d_ws;                 // N*128 f32 = 51.2 MB
  float* m   = h + (size_t)NN * CC;          // 51.2 MB
  float* agg = m + (size_t)NN * CC;          // 51.2 MB   (total 153.6 MB of ws)

  const int node_blocks = NN / 32;           // 3125 (exact)

  embed_kernel<<<NN, 128, 0, stream>>>(x, W_emb, b_emb, h);

  for (int l = 0; l < LL; ++l) {
    gemm_m_kernel<<<node_blocks, 128, 0, stream>>>(h, W + (size_t)l * CC * CC, m);
    hipMemsetAsync(agg, 0, (size_t)NN * CC * sizeof(float), stream);
    scatter_kernel<<<4096, 256, 0, stream>>>(m, eidx, ew, agg);
    gru_kernel<<<node_blocks, 128, 0, stream>>>(agg, h, W_ih, W_hh, b_ih, b_hh);
  }

  hipMemsetAsync(d_out, 0, (size_t)GG * sizeof(float), stream);
  prop_kernel<<<2048, 256, 0, stream>>>(h, batch, W_prop, b_prop, out);
}

// Round 2
// 4116.983 us; speedup vs baseline: 1.5775x; 1.5775x over previous
//
#include <hip/hip_runtime.h>

#define NN 100000
#define CC 128
#define EE 1600000
#define GG 1024
#define LL 5

__device__ __forceinline__ float sigmoidf_(float x) { return 1.0f / (1.0f + __expf(-x)); }
__device__ __forceinline__ float tanhf_(float x) {
  float xx = fminf(15.0f, fmaxf(-15.0f, x));
  float t = __expf(-2.0f * xx);
  return (1.0f - t) / (1.0f + t);
}
// f32 -> bf16 round-to-nearest-even (bit trick; NaN irrelevant here)
__device__ __forceinline__ unsigned short f2bf(float x) {
  unsigned int u = __float_as_uint(x);
  return (unsigned short)((u + 0x7fffu + ((u >> 16) & 1u)) >> 16);
}

// ---------------- CSR build (once per call; edge structure reused for 5 layers) ----

__global__ __launch_bounds__(256) void hist_kernel(const int* __restrict__ eidx,
                                                   int* __restrict__ deg)
{
  int e = blockIdx.x * blockDim.x + threadIdx.x;
  if (e < EE) atomicAdd(&deg[eidx[EE + e]], 1);
}

// per-1024-chunk sums
__global__ __launch_bounds__(256) void scan1_kernel(const int* __restrict__ deg,
                                                    int* __restrict__ bsum)
{
  __shared__ int red[4];
  int base = blockIdx.x * 1024 + threadIdx.x * 4;
  int s = 0;
  #pragma unroll
  for (int i = 0; i < 4; ++i) { int idx = base + i; if (idx < NN) s += deg[idx]; }
  #pragma unroll
  for (int off = 32; off; off >>= 1) s += __shfl_down(s, off, 64);
  if ((threadIdx.x & 63) == 0) red[threadIdx.x >> 6] = s;
  __syncthreads();
  if (threadIdx.x == 0) bsum[blockIdx.x] = red[0] + red[1] + red[2] + red[3];
}

// serial exclusive scan of the (tiny) block-sum array
__global__ void scan2_kernel(int* __restrict__ bsum, int nb)
{
  if (threadIdx.x == 0 && blockIdx.x == 0) {
    int acc = 0;
    for (int i = 0; i < nb; ++i) { int v = bsum[i]; bsum[i] = acc; acc += v; }
  }
}

// local exclusive scan + offset -> row_ptr, cursor
__global__ __launch_bounds__(256) void scan3_kernel(const int* __restrict__ deg,
                                                    const int* __restrict__ bsum,
                                                    int* __restrict__ row_ptr,
                                                    int* __restrict__ cursor)
{
  __shared__ int ts[256];
  const int tid = threadIdx.x;
  const int base = blockIdx.x * 1024 + tid * 4;
  int v[4]; int s = 0;
  #pragma unroll
  for (int i = 0; i < 4; ++i) { int idx = base + i; v[i] = (idx < NN) ? deg[idx] : 0; s += v[i]; }
  ts[tid] = s; __syncthreads();
  for (int off = 1; off < 256; off <<= 1) {
    int t = (tid >= off) ? ts[tid - off] : 0;
    __syncthreads();
    ts[tid] += t;
    __syncthreads();
  }
  int excl = bsum[blockIdx.x] + ts[tid] - s;
  #pragma unroll
  for (int i = 0; i < 4; ++i) {
    int idx = base + i;
    if (idx < NN) { row_ptr[idx] = excl; cursor[idx] = excl; excl += v[i]; }
  }
  if (blockIdx.x == 0 && tid == 0) row_ptr[NN] = EE;
}

__global__ __launch_bounds__(256) void fill_kernel(const int* __restrict__ eidx,
                                                   const float* __restrict__ ew,
                                                   int* __restrict__ cursor,
                                                   int* __restrict__ csr_src,
                                                   float* __restrict__ csr_w)
{
  int e = blockIdx.x * blockDim.x + threadIdx.x;
  if (e < EE) {
    int d = eidx[EE + e];
    int p = atomicAdd(&cursor[d], 1);
    csr_src[p] = eidx[e];
    csr_w[p] = ew[e];
  }
}

// ---------------- main pipeline ----------------

// h0 = x @ W_emb + b_emb   (x: [N,32], W_emb: [32,128])
__global__ __launch_bounds__(128) void embed_kernel(
    const float* __restrict__ x, const float* __restrict__ W_emb,
    const float* __restrict__ b_emb, float* __restrict__ h)
{
  const int node = blockIdx.x;
  const int c = threadIdx.x;
  float acc = b_emb[c];
  #pragma unroll
  for (int k = 0; k < 32; ++k)
    acc = fmaf(x[node * 32 + k], W_emb[k * CC + c], acc);
  h[(size_t)node * CC + c] = acc;
}

// m = bf16( h @ Wl )   (Wl row-major [k][c]); 32 nodes per block, 128 threads
__global__ __launch_bounds__(128) void gemm_m_kernel(
    const float* __restrict__ h, const float* __restrict__ W,
    unsigned short* __restrict__ m)
{
  __shared__ float As[32][133];
  __shared__ float Bs[32][132];
  const int nb = blockIdx.x * 32;
  const int tid = threadIdx.x;
  const int tx = tid & 15, ty = tid >> 4;
  const int j0 = tx * 8, n0 = ty * 4;

  {
    const int nr = tid >> 2, kc = (tid & 3) * 32;
    const float* src = h + (size_t)(nb + nr) * CC + kc;
    #pragma unroll
    for (int i = 0; i < 32; i += 4) {
      float4 v = *(const float4*)(src + i);
      As[nr][kc + i] = v.x; As[nr][kc + i + 1] = v.y;
      As[nr][kc + i + 2] = v.z; As[nr][kc + i + 3] = v.w;
    }
  }

  float acc[4][8];
  #pragma unroll
  for (int i = 0; i < 4; ++i)
    #pragma unroll
    for (int j = 0; j < 8; ++j) acc[i][j] = 0.0f;

  for (int kt = 0; kt < 4; ++kt) {
    __syncthreads();
    {
      const int kr = tid >> 2, cc0 = (tid & 3) * 32;
      const float* src = W + (size_t)(kt * 32 + kr) * CC + cc0;
      #pragma unroll
      for (int i = 0; i < 32; i += 4)
        *(float4*)&Bs[kr][cc0 + i] = *(const float4*)(src + i);
    }
    __syncthreads();
    #pragma unroll
    for (int k = 0; k < 32; ++k) {
      float a[4];
      #pragma unroll
      for (int i = 0; i < 4; ++i) a[i] = As[n0 + i][kt * 32 + k];
      float4 b0 = *(const float4*)&Bs[k][j0];
      float4 b1 = *(const float4*)&Bs[k][j0 + 4];
      float bv[8] = {b0.x, b0.y, b0.z, b0.w, b1.x, b1.y, b1.z, b1.w};
      #pragma unroll
      for (int i = 0; i < 4; ++i)
        #pragma unroll
        for (int j = 0; j < 8; ++j)
          acc[i][j] = fmaf(a[i], bv[j], acc[i][j]);
    }
  }

  #pragma unroll
  for (int i = 0; i < 4; ++i) {
    unsigned int p0 = (unsigned int)f2bf(acc[i][0]) | ((unsigned int)f2bf(acc[i][1]) << 16);
    unsigned int p1 = (unsigned int)f2bf(acc[i][2]) | ((unsigned int)f2bf(acc[i][3]) << 16);
    unsigned int p2 = (unsigned int)f2bf(acc[i][4]) | ((unsigned int)f2bf(acc[i][5]) << 16);
    unsigned int p3 = (unsigned int)f2bf(acc[i][6]) | ((unsigned int)f2bf(acc[i][7]) << 16);
    uint4* dst = (uint4*)(m + (size_t)(nb + n0 + i) * CC + j0);
    *dst = make_uint4(p0, p1, p2, p3);
  }
}

// agg[n] = sum_{e: dst=n} m[src_e] * w_e   — atomic-free gather via CSR.
// One wave per node; lane handles channels (2*lane, 2*lane+1) -> one u32 load/edge.
__global__ __launch_bounds__(256) void aggregate_kernel(
    const unsigned short* __restrict__ m, const int* __restrict__ row_ptr,
    const int* __restrict__ csr_src, const float* __restrict__ csr_w,
    float* __restrict__ agg)
{
  const int lane = threadIdx.x & 63;
  const int node = (blockIdx.x * blockDim.x + threadIdx.x) >> 6;
  if (node >= NN) return;
  const int beg = row_ptr[node], end = row_ptr[node + 1];
  float a0 = 0.0f, a1 = 0.0f;
  for (int j = beg; j < end; ++j) {
    const int s = csr_src[j];          // wave-uniform -> broadcast
    const float w = csr_w[j];
    unsigned int u = *(const unsigned int*)(m + (size_t)s * CC + 2 * lane);
    float lo = __uint_as_float(u << 16);
    float hi = __uint_as_float(u & 0xffff0000u);
    a0 = fmaf(lo, w, a0);
    a1 = fmaf(hi, w, a1);
  }
  float2* dst = (float2*)(agg + (size_t)node * CC + 2 * lane);
  *dst = make_float2(a0, a1);
}

// one gate-chunk matmul: acci = As @ W_ih[goff:goff+128]ᵀ, acch = Hs @ W_hh[...]ᵀ
__device__ __forceinline__ void gate_mm(
    const float (*As)[133], const float (*Hs)[133],
    float (*Wi)[132], float (*Wh)[132],
    const float* __restrict__ W_ih, const float* __restrict__ W_hh,
    int goff, int j0, int n0, int tid,
    float acci[4][8], float acch[4][8])
{
  #pragma unroll
  for (int i = 0; i < 4; ++i)
    #pragma unroll
    for (int j = 0; j < 8; ++j) { acci[i][j] = 0.0f; acch[i][j] = 0.0f; }

  for (int kt = 0; kt < 8; ++kt) {
    __syncthreads();
    {
      const float* si = W_ih + (size_t)(goff + tid) * CC + kt * 16;
      const float* sh = W_hh + (size_t)(goff + tid) * CC + kt * 16;
      #pragma unroll
      for (int i = 0; i < 16; i += 4) {
        float4 vi = *(const float4*)(si + i);
        Wi[i][tid] = vi.x; Wi[i + 1][tid] = vi.y; Wi[i + 2][tid] = vi.z; Wi[i + 3][tid] = vi.w;
        float4 vh = *(const float4*)(sh + i);
        Wh[i][tid] = vh.x; Wh[i + 1][tid] = vh.y; Wh[i + 2][tid] = vh.z; Wh[i + 3][tid] = vh.w;
      }
    }
    __syncthreads();
    #pragma unroll
    for (int k = 0; k < 16; ++k) {
      float a[4], hv[4];
      #pragma unroll
      for (int i = 0; i < 4; ++i) {
        a[i]  = As[n0 + i][kt * 16 + k];
        hv[i] = Hs[n0 + i][kt * 16 + k];
      }
      float4 wi0 = *(const float4*)&Wi[k][j0];
      float4 wi1 = *(const float4*)&Wi[k][j0 + 4];
      float4 wh0 = *(const float4*)&Wh[k][j0];
      float4 wh1 = *(const float4*)&Wh[k][j0 + 4];
      float wiv[8] = {wi0.x, wi0.y, wi0.z, wi0.w, wi1.x, wi1.y, wi1.z, wi1.w};
      float whv[8] = {wh0.x, wh0.y, wh0.z, wh0.w, wh1.x, wh1.y, wh1.z, wh1.w};
      #pragma unroll
      for (int i = 0; i < 4; ++i)
        #pragma unroll
        for (int j = 0; j < 8; ++j) {
          acci[i][j] = fmaf(a[i],  wiv[j], acci[i][j]);
          acch[i][j] = fmaf(hv[i], whv[j], acch[i][j]);
        }
    }
  }
}

// fused GRU cell: h = GRU(agg, h)
__global__ __launch_bounds__(128) void gru_kernel(
    const float* __restrict__ agg, float* __restrict__ h,
    const float* __restrict__ W_ih, const float* __restrict__ W_hh,
    const float* __restrict__ b_ih, const float* __restrict__ b_hh)
{
  __shared__ float As[32][133];
  __shared__ float Hs[32][133];
  __shared__ float Wi[16][132];
  __shared__ float Wh[16][132];
  const int nb = blockIdx.x * 32;
  const int tid = threadIdx.x;
  const int tx = tid & 15, ty = tid >> 4;
  const int j0 = tx * 8, n0 = ty * 4;

  {
    const int nr = tid >> 2, kc = (tid & 3) * 32;
    const float* sa = agg + (size_t)(nb + nr) * CC + kc;
    const float* sh = h + (size_t)(nb + nr) * CC + kc;
    #pragma unroll
    for (int i = 0; i < 32; i += 4) {
      float4 va = *(const float4*)(sa + i);
      As[nr][kc + i] = va.x; As[nr][kc + i + 1] = va.y;
      As[nr][kc + i + 2] = va.z; As[nr][kc + i + 3] = va.w;
      float4 vh = *(const float4*)(sh + i);
      Hs[nr][kc + i] = vh.x; Hs[nr][kc + i + 1] = vh.y;
      Hs[nr][kc + i + 2] = vh.z; Hs[nr][kc + i + 3] = vh.w;
    }
  }

  float acci[4][8], acch[4][8];
  float r_[4][8], nn_[4][8];

  gate_mm(As, Hs, Wi, Wh, W_ih, W_hh, 0, j0, n0, tid, acci, acch);
  #pragma unroll
  for (int i = 0; i < 4; ++i)
    #pragma unroll
    for (int j = 0; j < 8; ++j)
      r_[i][j] = sigmoidf_(acci[i][j] + acch[i][j] + b_ih[j0 + j] + b_hh[j0 + j]);

  gate_mm(As, Hs, Wi, Wh, W_ih, W_hh, 256, j0, n0, tid, acci, acch);
  #pragma unroll
  for (int i = 0; i < 4; ++i)
    #pragma unroll
    for (int j = 0; j < 8; ++j)
      nn_[i][j] = tanhf_(acci[i][j] + b_ih[256 + j0 + j] +
                         r_[i][j] * (acch[i][j] + b_hh[256 + j0 + j]));

  gate_mm(As, Hs, Wi, Wh, W_ih, W_hh, 128, j0, n0, tid, acci, acch);
  #pragma unroll
  for (int i = 0; i < 4; ++i) {
    float hn[8];
    #pragma unroll
    for (int j = 0; j < 8; ++j) {
      float z = sigmoidf_(acci[i][j] + acch[i][j] + b_ih[128 + j0 + j] + b_hh[128 + j0 + j]);
      hn[j] = (1.0f - z) * nn_[i][j] + z * Hs[n0 + i][j0 + j];
    }
    float* dst = h + (size_t)(nb + n0 + i) * CC + j0;
    *(float4*)dst       = make_float4(hn[0], hn[1], hn[2], hn[3]);
    *(float4*)(dst + 4) = make_float4(hn[4], hn[5], hn[6], hn[7]);
  }
}

// out[batch[n]] += h[n] . W_prop + b_prop   (wave per node)
__global__ __launch_bounds__(256) void prop_kernel(
    const float* __restrict__ h, const int* __restrict__ batch,
    const float* __restrict__ Wp, const float* __restrict__ bp,
    float* __restrict__ out)
{
  const int lane = threadIdx.x & 63;
  const int wid = (blockIdx.x * blockDim.x + threadIdx.x) >> 6;
  const int nw = (gridDim.x * blockDim.x) >> 6;
  for (int node = wid; node < NN; node += nw) {
    float v = h[(size_t)node * CC + lane] * Wp[lane]
            + h[(size_t)node * CC + 64 + lane] * Wp[64 + lane];
    #pragma unroll
    for (int off = 32; off > 0; off >>= 1) v += __shfl_down(v, off, 64);
    if (lane == 0) atomicAdd(&out[batch[node]], v + bp[0]);
  }
}

extern "C" void kernel_launch(void* const* d_in, const int* in_sizes, int n_in,
                              void* d_out, int out_size, void* d_ws, size_t ws_size,
                              hipStream_t stream)
{
  const float* x      = (const float*)d_in[0];
  const int*   eidx   = (const int*)d_in[1];
  const float* ew     = (const float*)d_in[2];
  const int*   batch  = (const int*)d_in[3];
  const float* W_emb  = (const float*)d_in[4];
  const float* b_emb  = (const float*)d_in[5];
  const float* W      = (const float*)d_in[6];
  const float* W_ih   = (const float*)d_in[7];
  const float* W_hh   = (const float*)d_in[8];
  const float* b_ih   = (const float*)d_in[9];
  const float* b_hh   = (const float*)d_in[10];
  const float* W_prop = (const float*)d_in[11];
  const float* b_prop = (const float*)d_in[12];
  float* out = (float*)d_out;

  // workspace layout (all 256B-aligned by construction; total ~142 MB)
  char* p = (char*)d_ws;
  float* h   = (float*)p;               p += (size_t)NN * CC * sizeof(float);   // 51.2 MB
  float* agg = (float*)p;               p += (size_t)NN * CC * sizeof(float);   // 51.2 MB
  unsigned short* m = (unsigned short*)p; p += (size_t)NN * CC * sizeof(short); // 25.6 MB
  int* csr_src = (int*)p;               p += (size_t)EE * sizeof(int);          // 6.4 MB
  float* csr_w = (float*)p;             p += (size_t)EE * sizeof(float);        // 6.4 MB
  int* deg     = (int*)p;               p += (size_t)(NN + 256) * sizeof(int);
  int* row_ptr = (int*)p;               p += (size_t)(NN + 256) * sizeof(int);
  int* cursor  = (int*)p;               p += (size_t)(NN + 256) * sizeof(int);
  int* bsum    = (int*)p;               p += 1024 * sizeof(int);

  const int node_blocks = NN / 32;      // 3125 (exact)
  const int NB_SCAN = (NN + 1023) / 1024;  // 98
  const int EB = (EE + 255) / 256;      // 6250

  // ---- CSR build (once; structure reused across the 5 layers) ----
  hipMemsetAsync(deg, 0, (size_t)NN * sizeof(int), stream);
  hist_kernel<<<EB, 256, 0, stream>>>(eidx, deg);
  scan1_kernel<<<NB_SCAN, 256, 0, stream>>>(deg, bsum);
  scan2_kernel<<<1, 64, 0, stream>>>(bsum, NB_SCAN);
  scan3_kernel<<<NB_SCAN, 256, 0, stream>>>(deg, bsum, row_ptr, cursor);
  fill_kernel<<<EB, 256, 0, stream>>>(eidx, ew, cursor, csr_src, csr_w);

  // ---- main pipeline ----
  embed_kernel<<<NN, 128, 0, stream>>>(x, W_emb, b_emb, h);

  for (int l = 0; l < LL; ++l) {
    gemm_m_kernel<<<node_blocks, 128, 0, stream>>>(h, W + (size_t)l * CC * CC, m);
    aggregate_kernel<<<(NN + 3) / 4, 256, 0, stream>>>(m, row_ptr, csr_src, csr_w, agg);
    gru_kernel<<<node_blocks, 128, 0, stream>>>(agg, h, W_ih, W_hh, b_ih, b_hh);
  }

  hipMemsetAsync(d_out, 0, (size_t)GG * sizeof(float), stream);
  prop_kernel<<<2048, 256, 0, stream>>>(h, batch, W_prop, b_prop, out);
}

// Round 3
// 1637.480 us; speedup vs baseline: 3.9661x; 2.5142x over previous
//
#include <hip/hip_runtime.h>

#define NN 100000
#define CC 128
#define EE 1600000
#define GG 1024
#define LL 5

typedef __attribute__((ext_vector_type(8))) short bf16x8;
typedef __attribute__((ext_vector_type(4))) float f32x4;

__device__ __forceinline__ float sigmoidf_(float x) { return 1.0f / (1.0f + __expf(-x)); }
__device__ __forceinline__ float tanhf_(float x) {
  float xx = fminf(15.0f, fmaxf(-15.0f, x));
  float t = __expf(-2.0f * xx);
  return (1.0f - t) / (1.0f + t);
}
// f32 -> bf16 round-to-nearest-even
__device__ __forceinline__ unsigned short f2bf(float x) {
  unsigned int u = __float_as_uint(x);
  return (unsigned short)((u + 0x7fffu + ((u >> 16) & 1u)) >> 16);
}
// 8 consecutive f32 -> bf16x8 fragment
__device__ __forceinline__ bf16x8 load_bf8_f32(const float* p) {
  float4 v0 = *(const float4*)p;
  float4 v1 = *(const float4*)(p + 4);
  union { bf16x8 v; unsigned int u[4]; } r;
  r.u[0] = (unsigned)f2bf(v0.x) | ((unsigned)f2bf(v0.y) << 16);
  r.u[1] = (unsigned)f2bf(v0.z) | ((unsigned)f2bf(v0.w) << 16);
  r.u[2] = (unsigned)f2bf(v1.x) | ((unsigned)f2bf(v1.y) << 16);
  r.u[3] = (unsigned)f2bf(v1.z) | ((unsigned)f2bf(v1.w) << 16);
  return r.v;
}

// ---------------- weight prepack: per-lane-linear B fragments ----------------
// dst[t] holds B[k][c] with k = ks*32 + 8*(l>>4) + i, c = cb*16 + (l&15),
// t = ((cb*nKS+ks)*64 + l)*8 + i.  transposed: src[c*ld + k], else src[k*ld + c].
__global__ __launch_bounds__(256) void pack_kernel(
    const float* __restrict__ src, unsigned short* __restrict__ dst,
    int nKS, int transposed, int ld)
{
  int t = blockIdx.x * 256 + threadIdx.x;
  int i = t & 7, l = (t >> 3) & 63, q = t >> 9;
  int ks = q % nKS, cb = q / nKS;
  int k = ks * 32 + 8 * (l >> 4) + i;
  int c = cb * 16 + (l & 15);
  float v = transposed ? src[(size_t)c * ld + k] : src[(size_t)k * ld + c];
  dst[t] = f2bf(v);
}

// ---------------- CSR build (once per call) ----------------

__global__ __launch_bounds__(256) void hist_kernel(const int* __restrict__ eidx,
                                                   int* __restrict__ deg)
{
  int e = blockIdx.x * blockDim.x + threadIdx.x;
  if (e < EE) atomicAdd(&deg[eidx[EE + e]], 1);
}

__global__ __launch_bounds__(256) void scan1_kernel(const int* __restrict__ deg,
                                                    int* __restrict__ bsum)
{
  __shared__ int red[4];
  int base = blockIdx.x * 1024 + threadIdx.x * 4;
  int s = 0;
  #pragma unroll
  for (int i = 0; i < 4; ++i) { int idx = base + i; if (idx < NN) s += deg[idx]; }
  #pragma unroll
  for (int off = 32; off; off >>= 1) s += __shfl_down(s, off, 64);
  if ((threadIdx.x & 63) == 0) red[threadIdx.x >> 6] = s;
  __syncthreads();
  if (threadIdx.x == 0) bsum[blockIdx.x] = red[0] + red[1] + red[2] + red[3];
}

__global__ void scan2_kernel(int* __restrict__ bsum, int nb)
{
  if (threadIdx.x == 0 && blockIdx.x == 0) {
    int acc = 0;
    for (int i = 0; i < nb; ++i) { int v = bsum[i]; bsum[i] = acc; acc += v; }
  }
}

__global__ __launch_bounds__(256) void scan3_kernel(const int* __restrict__ deg,
                                                    const int* __restrict__ bsum,
                                                    int* __restrict__ row_ptr,
                                                    int* __restrict__ cursor)
{
  __shared__ int ts[256];
  const int tid = threadIdx.x;
  const int base = blockIdx.x * 1024 + tid * 4;
  int v[4]; int s = 0;
  #pragma unroll
  for (int i = 0; i < 4; ++i) { int idx = base + i; v[i] = (idx < NN) ? deg[idx] : 0; s += v[i]; }
  ts[tid] = s; __syncthreads();
  for (int off = 1; off < 256; off <<= 1) {
    int t = (tid >= off) ? ts[tid - off] : 0;
    __syncthreads();
    ts[tid] += t;
    __syncthreads();
  }
  int excl = bsum[blockIdx.x] + ts[tid] - s;
  #pragma unroll
  for (int i = 0; i < 4; ++i) {
    int idx = base + i;
    if (idx < NN) { row_ptr[idx] = excl; cursor[idx] = excl; excl += v[i]; }
  }
  if (blockIdx.x == 0 && tid == 0) row_ptr[NN] = EE;
}

__global__ __launch_bounds__(256) void fill_kernel(const int* __restrict__ eidx,
                                                   const float* __restrict__ ew,
                                                   int* __restrict__ cursor,
                                                   int* __restrict__ csr_src,
                                                   float* __restrict__ csr_w)
{
  int e = blockIdx.x * blockDim.x + threadIdx.x;
  if (e < EE) {
    int d = eidx[EE + e];
    int p = atomicAdd(&cursor[d], 1);
    csr_src[p] = eidx[e];
    csr_w[p] = ew[e];
  }
}

// ---------------- main pipeline ----------------

// h0 = x @ W_emb + b_emb   (x: [N,32])
__global__ __launch_bounds__(128) void embed_kernel(
    const float* __restrict__ x, const float* __restrict__ W_emb,
    const float* __restrict__ b_emb, float* __restrict__ h)
{
  const int node = blockIdx.x;
  const int c = threadIdx.x;
  float acc = b_emb[c];
  #pragma unroll
  for (int k = 0; k < 32; ++k)
    acc = fmaf(x[node * 32 + k], W_emb[k * CC + c], acc);
  h[(size_t)node * CC + c] = acc;
}

// m = bf16( h @ Wl ) via MFMA. 64 nodes/block, 4 waves x 16 nodes. No LDS.
__global__ __launch_bounds__(256) void gemm_m_kernel(
    const float* __restrict__ h, const unsigned short* __restrict__ Wp,
    unsigned short* __restrict__ m)
{
  const int lane = threadIdx.x & 63;
  const int wave = threadIdx.x >> 6;
  const int node0 = blockIdx.x * 64 + wave * 16;
  if (node0 >= NN) return;
  const int col16 = lane & 15, grp = lane >> 4;

  const float* arow = h + (size_t)(node0 + col16) * CC + grp * 8;
  bf16x8 a[4];
  #pragma unroll
  for (int ks = 0; ks < 4; ++ks) a[ks] = load_bf8_f32(arow + ks * 32);

  #pragma unroll
  for (int cb = 0; cb < 8; ++cb) {
    f32x4 acc = {0.f, 0.f, 0.f, 0.f};
    #pragma unroll
    for (int ks = 0; ks < 4; ++ks) {
      bf16x8 b = *(const bf16x8*)(Wp + (size_t)((cb * 4 + ks) * 64 + lane) * 8);
      acc = __builtin_amdgcn_mfma_f32_16x16x32_bf16(a[ks], b, acc, 0, 0, 0);
    }
    #pragma unroll
    for (int r = 0; r < 4; ++r)
      m[(size_t)(node0 + grp * 4 + r) * CC + cb * 16 + col16] = f2bf(acc[r]);
  }
}

// agg_bf[n] = bf16( sum_{e:dst=n} m[src_e] * w_e )  — CSR gather, wave per node
__global__ __launch_bounds__(256) void aggregate_kernel(
    const unsigned short* __restrict__ m, const int* __restrict__ row_ptr,
    const int* __restrict__ csr_src, const float* __restrict__ csr_w,
    unsigned short* __restrict__ agg_bf)
{
  const int lane = threadIdx.x & 63;
  const int node = (blockIdx.x * blockDim.x + threadIdx.x) >> 6;
  if (node >= NN) return;
  const int beg = row_ptr[node], end = row_ptr[node + 1];
  float a0 = 0.0f, a1 = 0.0f;
  for (int j = beg; j < end; ++j) {
    const int s = csr_src[j];          // wave-uniform -> broadcast
    const float w = csr_w[j];
    unsigned int u = *(const unsigned int*)(m + (size_t)s * CC + 2 * lane);
    float lo = __uint_as_float(u << 16);
    float hi = __uint_as_float(u & 0xffff0000u);
    a0 = fmaf(lo, w, a0);
    a1 = fmaf(hi, w, a1);
  }
  unsigned int u = (unsigned)f2bf(a0) | ((unsigned)f2bf(a1) << 16);
  *(unsigned int*)(agg_bf + (size_t)node * CC + 2 * lane) = u;
}

// fused GRU cell via MFMA: h = GRU(agg, h). 64 nodes/block, 4 waves. No LDS.
// gi = agg @ W_ih^T (cols: r 0..127 | z 128..255 | n 256..383), gh = h @ W_hh^T.
__global__ __launch_bounds__(256) void gru_kernel(
    const unsigned short* __restrict__ agg_bf, float* __restrict__ h,
    const unsigned short* __restrict__ Wih_p, const unsigned short* __restrict__ Whh_p,
    const float* __restrict__ b_ih, const float* __restrict__ b_hh)
{
  const int lane = threadIdx.x & 63;
  const int wave = threadIdx.x >> 6;
  const int node0 = blockIdx.x * 64 + wave * 16;
  if (node0 >= NN) return;
  const int col16 = lane & 15, grp = lane >> 4;

  bf16x8 aA[4], aH[4];
  {
    const unsigned short* arow = agg_bf + (size_t)(node0 + col16) * CC + grp * 8;
    const float* hrow = h + (size_t)(node0 + col16) * CC + grp * 8;
    #pragma unroll
    for (int ks = 0; ks < 4; ++ks) {
      aA[ks] = *(const bf16x8*)(arow + ks * 32);
      aH[ks] = load_bf8_f32(hrow + ks * 32);
    }
  }

  float rg[8][4], ng[8][4];

  // ---- r gate (col-blocks 0..7) ----
  #pragma unroll
  for (int cb = 0; cb < 8; ++cb) {
    f32x4 ai = {0.f, 0.f, 0.f, 0.f}, ah = {0.f, 0.f, 0.f, 0.f};
    #pragma unroll
    for (int ks = 0; ks < 4; ++ks) {
      bf16x8 bi = *(const bf16x8*)(Wih_p + (size_t)((cb * 4 + ks) * 64 + lane) * 8);
      bf16x8 bh = *(const bf16x8*)(Whh_p + (size_t)((cb * 4 + ks) * 64 + lane) * 8);
      ai = __builtin_amdgcn_mfma_f32_16x16x32_bf16(aA[ks], bi, ai, 0, 0, 0);
      ah = __builtin_amdgcn_mfma_f32_16x16x32_bf16(aH[ks], bh, ah, 0, 0, 0);
    }
    const int o = cb * 16 + col16;
    const float bi_ = b_ih[o], bh_ = b_hh[o];
    #pragma unroll
    for (int r = 0; r < 4; ++r)
      rg[cb][r] = sigmoidf_(ai[r] + ah[r] + bi_ + bh_);
  }

  // ---- n gate (col-blocks 16..23): n = tanh(i_n + b_in + r*(h_n + b_hn)) ----
  #pragma unroll
  for (int cb = 0; cb < 8; ++cb) {
    f32x4 ai = {0.f, 0.f, 0.f, 0.f}, ah = {0.f, 0.f, 0.f, 0.f};
    #pragma unroll
    for (int ks = 0; ks < 4; ++ks) {
      bf16x8 bi = *(const bf16x8*)(Wih_p + (size_t)(((16 + cb) * 4 + ks) * 64 + lane) * 8);
      bf16x8 bh = *(const bf16x8*)(Whh_p + (size_t)(((16 + cb) * 4 + ks) * 64 + lane) * 8);
      ai = __builtin_amdgcn_mfma_f32_16x16x32_bf16(aA[ks], bi, ai, 0, 0, 0);
      ah = __builtin_amdgcn_mfma_f32_16x16x32_bf16(aH[ks], bh, ah, 0, 0, 0);
    }
    const int o = 256 + cb * 16 + col16;
    const float bi_ = b_ih[o], bh_ = b_hh[o];
    #pragma unroll
    for (int r = 0; r < 4; ++r)
      ng[cb][r] = tanhf_(ai[r] + bi_ + rg[cb][r] * (ah[r] + bh_));
  }

  // ---- z gate (col-blocks 8..15) + blend + store ----
  #pragma unroll
  for (int cb = 0; cb < 8; ++cb) {
    f32x4 ai = {0.f, 0.f, 0.f, 0.f}, ah = {0.f, 0.f, 0.f, 0.f};
    #pragma unroll
    for (int ks = 0; ks < 4; ++ks) {
      bf16x8 bi = *(const bf16x8*)(Wih_p + (size_t)(((8 + cb) * 4 + ks) * 64 + lane) * 8);
      bf16x8 bh = *(const bf16x8*)(Whh_p + (size_t)(((8 + cb) * 4 + ks) * 64 + lane) * 8);
      ai = __builtin_amdgcn_mfma_f32_16x16x32_bf16(aA[ks], bi, ai, 0, 0, 0);
      ah = __builtin_amdgcn_mfma_f32_16x16x32_bf16(aH[ks], bh, ah, 0, 0, 0);
    }
    const int o = 128 + cb * 16 + col16;
    const float bi_ = b_ih[o], bh_ = b_hh[o];
    #pragma unroll
    for (int r = 0; r < 4; ++r) {
      float z = sigmoidf_(ai[r] + ah[r] + bi_ + bh_);
      size_t idx = (size_t)(node0 + grp * 4 + r) * CC + cb * 16 + col16;
      float ho = h[idx];
      h[idx] = (1.0f - z) * ng[cb][r] + z * ho;
    }
  }
}

// out[batch[n]] += h[n] . W_prop + b_prop   (wave per node)
__global__ __launch_bounds__(256) void prop_kernel(
    const float* __restrict__ h, const int* __restrict__ batch,
    const float* __restrict__ Wp, const float* __restrict__ bp,
    float* __restrict__ out)
{
  const int lane = threadIdx.x & 63;
  const int wid = (blockIdx.x * blockDim.x + threadIdx.x) >> 6;
  const int nw = (gridDim.x * blockDim.x) >> 6;
  for (int node = wid; node < NN; node += nw) {
    float v = h[(size_t)node * CC + lane] * Wp[lane]
            + h[(size_t)node * CC + 64 + lane] * Wp[64 + lane];
    #pragma unroll
    for (int off = 32; off > 0; off >>= 1) v += __shfl_down(v, off, 64);
    if (lane == 0) atomicAdd(&out[batch[node]], v + bp[0]);
  }
}

extern "C" void kernel_launch(void* const* d_in, const int* in_sizes, int n_in,
                              void* d_out, int out_size, void* d_ws, size_t ws_size,
                              hipStream_t stream)
{
  const float* x      = (const float*)d_in[0];
  const int*   eidx   = (const int*)d_in[1];
  const float* ew     = (const float*)d_in[2];
  const int*   batch  = (const int*)d_in[3];
  const float* W_emb  = (const float*)d_in[4];
  const float* b_emb  = (const float*)d_in[5];
  const float* W      = (const float*)d_in[6];
  const float* W_ih   = (const float*)d_in[7];
  const float* W_hh   = (const float*)d_in[8];
  const float* b_ih   = (const float*)d_in[9];
  const float* b_hh   = (const float*)d_in[10];
  const float* W_prop = (const float*)d_in[11];
  const float* b_prop = (const float*)d_in[12];
  float* out = (float*)d_out;

  // workspace layout (~117 MB)
  char* p = (char*)d_ws;
  float* h            = (float*)p;          p += (size_t)NN * CC * sizeof(float);  // 51.2 MB
  unsigned short* m   = (unsigned short*)p; p += (size_t)NN * CC * sizeof(short);  // 25.6 MB
  unsigned short* agg = (unsigned short*)p; p += (size_t)NN * CC * sizeof(short);  // 25.6 MB
  int* csr_src        = (int*)p;            p += (size_t)EE * sizeof(int);         // 6.4 MB
  float* csr_w        = (float*)p;          p += (size_t)EE * sizeof(float);       // 6.4 MB
  unsigned short* Wl_p  = (unsigned short*)p; p += (size_t)LL * 16384 * sizeof(short);
  unsigned short* Wih_p = (unsigned short*)p; p += (size_t)24 * 4 * 512 * sizeof(short);
  unsigned short* Whh_p = (unsigned short*)p; p += (size_t)24 * 4 * 512 * sizeof(short);
  int* deg     = (int*)p;                   p += (size_t)(NN + 256) * sizeof(int);
  int* row_ptr = (int*)p;                   p += (size_t)(NN + 256) * sizeof(int);
  int* cursor  = (int*)p;                   p += (size_t)(NN + 256) * sizeof(int);
  int* bsum    = (int*)p;                   p += 1024 * sizeof(int);

  const int NB_SCAN = (NN + 1023) / 1024;   // 98
  const int EB = (EE + 255) / 256;          // 6250
  const int MB = (NN + 63) / 64;            // 1563

  // ---- weight prepack (tiny, once per call) ----
  for (int l = 0; l < LL; ++l)
    pack_kernel<<<64, 256, 0, stream>>>(W + (size_t)l * CC * CC, Wl_p + (size_t)l * 16384, 4, 0, CC);
  pack_kernel<<<192, 256, 0, stream>>>(W_ih, Wih_p, 4, 1, CC);
  pack_kernel<<<192, 256, 0, stream>>>(W_hh, Whh_p, 4, 1, CC);

  // ---- CSR build ----
  hipMemsetAsync(deg, 0, (size_t)NN * sizeof(int), stream);
  hist_kernel<<<EB, 256, 0, stream>>>(eidx, deg);
  scan1_kernel<<<NB_SCAN, 256, 0, stream>>>(deg, bsum);
  scan2_kernel<<<1, 64, 0, stream>>>(bsum, NB_SCAN);
  scan3_kernel<<<NB_SCAN, 256, 0, stream>>>(deg, bsum, row_ptr, cursor);
  fill_kernel<<<EB, 256, 0, stream>>>(eidx, ew, cursor, csr_src, csr_w);

  // ---- main pipeline ----
  embed_kernel<<<NN, 128, 0, stream>>>(x, W_emb, b_emb, h);

  for (int l = 0; l < LL; ++l) {
    gemm_m_kernel<<<MB, 256, 0, stream>>>(h, Wl_p + (size_t)l * 16384, m);
    aggregate_kernel<<<(NN + 3) / 4, 256, 0, stream>>>(m, row_ptr, csr_src, csr_w, agg);
    gru_kernel<<<MB, 256, 0, stream>>>(agg, h, Wih_p, Whh_p, b_ih, b_hh);
  }

  hipMemsetAsync(d_out, 0, (size_t)GG * sizeof(float), stream);
  prop_kernel<<<2048, 256, 0, stream>>>(h, batch, W_prop, b_prop, out);
}

// Round 4
// 1195.274 us; speedup vs baseline: 5.4334x; 1.3700x over previous
//
#include <hip/hip_runtime.h>

#define NN 100000
#define CC 128
#define EE 1600000
#define GG 1024
#define LL 5

typedef __attribute__((ext_vector_type(8))) short bf16x8;
typedef __attribute__((ext_vector_type(4))) float f32x4;

__device__ __forceinline__ float sigmoidf_(float x) { return 1.0f / (1.0f + __expf(-x)); }
__device__ __forceinline__ float tanhf_(float x) {
  float xx = fminf(15.0f, fmaxf(-15.0f, x));
  float t = __expf(-2.0f * xx);
  return (1.0f - t) / (1.0f + t);
}
// f32 -> bf16 round-to-nearest-even
__device__ __forceinline__ unsigned short f2bf(float x) {
  unsigned int u = __float_as_uint(x);
  return (unsigned short)((u + 0x7fffu + ((u >> 16) & 1u)) >> 16);
}
__device__ __forceinline__ float bflo(unsigned int u) { return __uint_as_float(u << 16); }
__device__ __forceinline__ float bfhi(unsigned int u) { return __uint_as_float(u & 0xffff0000u); }
// 8 consecutive f32 -> bf16x8 fragment
__device__ __forceinline__ bf16x8 load_bf8_f32(const float* p) {
  float4 v0 = *(const float4*)p;
  float4 v1 = *(const float4*)(p + 4);
  union { bf16x8 v; unsigned int u[4]; } r;
  r.u[0] = (unsigned)f2bf(v0.x) | ((unsigned)f2bf(v0.y) << 16);
  r.u[1] = (unsigned)f2bf(v0.z) | ((unsigned)f2bf(v0.w) << 16);
  r.u[2] = (unsigned)f2bf(v1.x) | ((unsigned)f2bf(v1.y) << 16);
  r.u[3] = (unsigned)f2bf(v1.z) | ((unsigned)f2bf(v1.w) << 16);
  return r.v;
}

// ---------------- weight prepack: per-lane-linear B fragments ----------------
// dst[t] holds B[k][c] with k = ks*32 + 8*(l>>4) + i, c = cb*16 + (l&15),
// t = ((cb*nKS+ks)*64 + l)*8 + i.  transposed: src[c*ld + k], else src[k*ld + c].
__global__ __launch_bounds__(256) void pack_kernel(
    const float* __restrict__ src, unsigned short* __restrict__ dst,
    int nKS, int transposed, int ld)
{
  int t = blockIdx.x * 256 + threadIdx.x;
  int i = t & 7, l = (t >> 3) & 63, q = t >> 9;
  int ks = q % nKS, cb = q / nKS;
  int k = ks * 32 + 8 * (l >> 4) + i;
  int c = cb * 16 + (l & 15);
  float v = transposed ? src[(size_t)c * ld + k] : src[(size_t)k * ld + c];
  dst[t] = f2bf(v);
}

// ---------------- CSR build (once per call) ----------------

__global__ __launch_bounds__(256) void hist_kernel(const int* __restrict__ eidx,
                                                   int* __restrict__ deg)
{
  int e = blockIdx.x * blockDim.x + threadIdx.x;
  if (e < EE) atomicAdd(&deg[eidx[EE + e]], 1);
}

__global__ __launch_bounds__(256) void scan1_kernel(const int* __restrict__ deg,
                                                    int* __restrict__ bsum)
{
  __shared__ int red[4];
  int base = blockIdx.x * 1024 + threadIdx.x * 4;
  int s = 0;
  #pragma unroll
  for (int i = 0; i < 4; ++i) { int idx = base + i; if (idx < NN) s += deg[idx]; }
  #pragma unroll
  for (int off = 32; off; off >>= 1) s += __shfl_down(s, off, 64);
  if ((threadIdx.x & 63) == 0) red[threadIdx.x >> 6] = s;
  __syncthreads();
  if (threadIdx.x == 0) bsum[blockIdx.x] = red[0] + red[1] + red[2] + red[3];
}

__global__ void scan2_kernel(int* __restrict__ bsum, int nb)
{
  if (threadIdx.x == 0 && blockIdx.x == 0) {
    int acc = 0;
    for (int i = 0; i < nb; ++i) { int v = bsum[i]; bsum[i] = acc; acc += v; }
  }
}

__global__ __launch_bounds__(256) void scan3_kernel(const int* __restrict__ deg,
                                                    const int* __restrict__ bsum,
                                                    int* __restrict__ row_ptr,
                                                    int* __restrict__ cursor)
{
  __shared__ int ts[256];
  const int tid = threadIdx.x;
  const int base = blockIdx.x * 1024 + tid * 4;
  int v[4]; int s = 0;
  #pragma unroll
  for (int i = 0; i < 4; ++i) { int idx = base + i; v[i] = (idx < NN) ? deg[idx] : 0; s += v[i]; }
  ts[tid] = s; __syncthreads();
  for (int off = 1; off < 256; off <<= 1) {
    int t = (tid >= off) ? ts[tid - off] : 0;
    __syncthreads();
    ts[tid] += t;
    __syncthreads();
  }
  int excl = bsum[blockIdx.x] + ts[tid] - s;
  #pragma unroll
  for (int i = 0; i < 4; ++i) {
    int idx = base + i;
    if (idx < NN) { row_ptr[idx] = excl; cursor[idx] = excl; excl += v[i]; }
  }
  if (blockIdx.x == 0 && tid == 0) row_ptr[NN] = EE;
}

__global__ __launch_bounds__(256) void fill_kernel(const int* __restrict__ eidx,
                                                   const float* __restrict__ ew,
                                                   int* __restrict__ cursor,
                                                   int* __restrict__ csr_src,
                                                   float* __restrict__ csr_w)
{
  int e = blockIdx.x * blockDim.x + threadIdx.x;
  if (e < EE) {
    int d = eidx[EE + e];
    int p = atomicAdd(&cursor[d], 1);
    csr_src[p] = eidx[e];
    csr_w[p] = ew[e];
  }
}

// ---------------- main pipeline ----------------

// h0 = x @ W_emb + b_emb   (x: [N,32])
__global__ __launch_bounds__(128) void embed_kernel(
    const float* __restrict__ x, const float* __restrict__ W_emb,
    const float* __restrict__ b_emb, float* __restrict__ h)
{
  const int node = blockIdx.x;
  const int c = threadIdx.x;
  float acc = b_emb[c];
  #pragma unroll
  for (int k = 0; k < 32; ++k)
    acc = fmaf(x[node * 32 + k], W_emb[k * CC + c], acc);
  h[(size_t)node * CC + c] = acc;
}

// m = bf16( h @ Wl ) via MFMA. 64 nodes/block, 4 waves x 16 nodes. No LDS.
__global__ __launch_bounds__(256) void gemm_m_kernel(
    const float* __restrict__ h, const unsigned short* __restrict__ Wp,
    unsigned short* __restrict__ m)
{
  const int lane = threadIdx.x & 63;
  const int wave = threadIdx.x >> 6;
  const int node0 = blockIdx.x * 64 + wave * 16;
  if (node0 >= NN) return;
  const int col16 = lane & 15, grp = lane >> 4;

  const float* arow = h + (size_t)(node0 + col16) * CC + grp * 8;
  bf16x8 a[4];
  #pragma unroll
  for (int ks = 0; ks < 4; ++ks) a[ks] = load_bf8_f32(arow + ks * 32);

  #pragma unroll
  for (int cb = 0; cb < 8; ++cb) {
    f32x4 acc = {0.f, 0.f, 0.f, 0.f};
    #pragma unroll
    for (int ks = 0; ks < 4; ++ks) {
      bf16x8 b = *(const bf16x8*)(Wp + (size_t)((cb * 4 + ks) * 64 + lane) * 8);
      acc = __builtin_amdgcn_mfma_f32_16x16x32_bf16(a[ks], b, acc, 0, 0, 0);
    }
    #pragma unroll
    for (int r = 0; r < 4; ++r)
      m[(size_t)(node0 + grp * 4 + r) * CC + cb * 16 + col16] = f2bf(acc[r]);
  }
}

// agg_bf[n] = bf16( sum_{e:dst=n} m[src_e] * w_e )  — CSR gather.
// Wave split into 4 quarters of 16 lanes; quarter q handles edge j+q, each lane
// loads 16 B (8 channels). 2 batches per iteration -> 8 edges in flight.
// Cross-quarter combine via shfl_xor(16/32) once per node.
__global__ __launch_bounds__(256) void aggregate_kernel(
    const unsigned short* __restrict__ m, const int* __restrict__ row_ptr,
    const int* __restrict__ csr_src, const float* __restrict__ csr_w,
    unsigned short* __restrict__ agg_bf)
{
  const int lane = threadIdx.x & 63;
  const int node = (blockIdx.x * blockDim.x + threadIdx.x) >> 6;
  if (node >= NN) return;
  const int q = lane >> 4;          // quarter 0..3
  const int t = lane & 15;          // lane within quarter
  const int beg = row_ptr[node], end = row_ptr[node + 1];

  float acc[8] = {0.f, 0.f, 0.f, 0.f, 0.f, 0.f, 0.f, 0.f};
  const int last = end - 1;

  for (int j = beg; j < end; j += 8) {
    const int e0 = j + q, e1 = j + 4 + q;
    const int i0 = min(e0, last), i1 = min(e1, last);
    const int s0 = csr_src[i0], s1 = csr_src[i1];
    const float w0 = (e0 < end) ? csr_w[i0] : 0.0f;
    const float w1 = (e1 < end) ? csr_w[i1] : 0.0f;
    const uint4 u0 = *(const uint4*)(m + (size_t)s0 * CC + t * 8);
    const uint4 u1 = *(const uint4*)(m + (size_t)s1 * CC + t * 8);
    acc[0] = fmaf(bflo(u0.x), w0, acc[0]); acc[1] = fmaf(bfhi(u0.x), w0, acc[1]);
    acc[2] = fmaf(bflo(u0.y), w0, acc[2]); acc[3] = fmaf(bfhi(u0.y), w0, acc[3]);
    acc[4] = fmaf(bflo(u0.z), w0, acc[4]); acc[5] = fmaf(bfhi(u0.z), w0, acc[5]);
    acc[6] = fmaf(bflo(u0.w), w0, acc[6]); acc[7] = fmaf(bfhi(u0.w), w0, acc[7]);
    acc[0] = fmaf(bflo(u1.x), w1, acc[0]); acc[1] = fmaf(bfhi(u1.x), w1, acc[1]);
    acc[2] = fmaf(bflo(u1.y), w1, acc[2]); acc[3] = fmaf(bfhi(u1.y), w1, acc[3]);
    acc[4] = fmaf(bflo(u1.z), w1, acc[4]); acc[5] = fmaf(bfhi(u1.z), w1, acc[5]);
    acc[6] = fmaf(bflo(u1.w), w1, acc[6]); acc[7] = fmaf(bfhi(u1.w), w1, acc[7]);
  }

  // combine the 4 quarters (channels identical across quarters)
  #pragma unroll
  for (int i = 0; i < 8; ++i) {
    acc[i] += __shfl_xor(acc[i], 16, 64);
    acc[i] += __shfl_xor(acc[i], 32, 64);
  }

  if (q == 0) {
    uint4 o;
    o.x = (unsigned)f2bf(acc[0]) | ((unsigned)f2bf(acc[1]) << 16);
    o.y = (unsigned)f2bf(acc[2]) | ((unsigned)f2bf(acc[3]) << 16);
    o.z = (unsigned)f2bf(acc[4]) | ((unsigned)f2bf(acc[5]) << 16);
    o.w = (unsigned)f2bf(acc[6]) | ((unsigned)f2bf(acc[7]) << 16);
    *(uint4*)(agg_bf + (size_t)node * CC + t * 8) = o;
  }
}

// fused GRU cell via MFMA: h = GRU(agg, h). 64 nodes/block, 4 waves. No LDS.
// gi = agg @ W_ih^T (cols: r 0..127 | z 128..255 | n 256..383), gh = h @ W_hh^T.
__global__ __launch_bounds__(256) void gru_kernel(
    const unsigned short* __restrict__ agg_bf, float* __restrict__ h,
    const unsigned short* __restrict__ Wih_p, const unsigned short* __restrict__ Whh_p,
    const float* __restrict__ b_ih, const float* __restrict__ b_hh)
{
  const int lane = threadIdx.x & 63;
  const int wave = threadIdx.x >> 6;
  const int node0 = blockIdx.x * 64 + wave * 16;
  if (node0 >= NN) return;
  const int col16 = lane & 15, grp = lane >> 4;

  bf16x8 aA[4], aH[4];
  {
    const unsigned short* arow = agg_bf + (size_t)(node0 + col16) * CC + grp * 8;
    const float* hrow = h + (size_t)(node0 + col16) * CC + grp * 8;
    #pragma unroll
    for (int ks = 0; ks < 4; ++ks) {
      aA[ks] = *(const bf16x8*)(arow + ks * 32);
      aH[ks] = load_bf8_f32(hrow + ks * 32);
    }
  }

  float rg[8][4], ng[8][4];

  // ---- r gate (col-blocks 0..7) ----
  #pragma unroll
  for (int cb = 0; cb < 8; ++cb) {
    f32x4 ai = {0.f, 0.f, 0.f, 0.f}, ah = {0.f, 0.f, 0.f, 0.f};
    #pragma unroll
    for (int ks = 0; ks < 4; ++ks) {
      bf16x8 bi = *(const bf16x8*)(Wih_p + (size_t)((cb * 4 + ks) * 64 + lane) * 8);
      bf16x8 bh = *(const bf16x8*)(Whh_p + (size_t)((cb * 4 + ks) * 64 + lane) * 8);
      ai = __builtin_amdgcn_mfma_f32_16x16x32_bf16(aA[ks], bi, ai, 0, 0, 0);
      ah = __builtin_amdgcn_mfma_f32_16x16x32_bf16(aH[ks], bh, ah, 0, 0, 0);
    }
    const int o = cb * 16 + col16;
    const float bi_ = b_ih[o], bh_ = b_hh[o];
    #pragma unroll
    for (int r = 0; r < 4; ++r)
      rg[cb][r] = sigmoidf_(ai[r] + ah[r] + bi_ + bh_);
  }

  // ---- n gate (col-blocks 16..23): n = tanh(i_n + b_in + r*(h_n + b_hn)) ----
  #pragma unroll
  for (int cb = 0; cb < 8; ++cb) {
    f32x4 ai = {0.f, 0.f, 0.f, 0.f}, ah = {0.f, 0.f, 0.f, 0.f};
    #pragma unroll
    for (int ks = 0; ks < 4; ++ks) {
      bf16x8 bi = *(const bf16x8*)(Wih_p + (size_t)(((16 + cb) * 4 + ks) * 64 + lane) * 8);
      bf16x8 bh = *(const bf16x8*)(Whh_p + (size_t)(((16 + cb) * 4 + ks) * 64 + lane) * 8);
      ai = __builtin_amdgcn_mfma_f32_16x16x32_bf16(aA[ks], bi, ai, 0, 0, 0);
      ah = __builtin_amdgcn_mfma_f32_16x16x32_bf16(aH[ks], bh, ah, 0, 0, 0);
    }
    const int o = 256 + cb * 16 + col16;
    const float bi_ = b_ih[o], bh_ = b_hh[o];
    #pragma unroll
    for (int r = 0; r < 4; ++r)
      ng[cb][r] = tanhf_(ai[r] + bi_ + rg[cb][r] * (ah[r] + bh_));
  }

  // ---- z gate (col-blocks 8..15) + blend + store ----
  #pragma unroll
  for (int cb = 0; cb < 8; ++cb) {
    f32x4 ai = {0.f, 0.f, 0.f, 0.f}, ah = {0.f, 0.f, 0.f, 0.f};
    #pragma unroll
    for (int ks = 0; ks < 4; ++ks) {
      bf16x8 bi = *(const bf16x8*)(Wih_p + (size_t)(((8 + cb) * 4 + ks) * 64 + lane) * 8);
      bf16x8 bh = *(const bf16x8*)(Whh_p + (size_t)(((8 + cb) * 4 + ks) * 64 + lane) * 8);
      ai = __builtin_amdgcn_mfma_f32_16x16x32_bf16(aA[ks], bi, ai, 0, 0, 0);
      ah = __builtin_amdgcn_mfma_f32_16x16x32_bf16(aH[ks], bh, ah, 0, 0, 0);
    }
    const int o = 128 + cb * 16 + col16;
    const float bi_ = b_ih[o], bh_ = b_hh[o];
    #pragma unroll
    for (int r = 0; r < 4; ++r) {
      float z = sigmoidf_(ai[r] + ah[r] + bi_ + bh_);
      size_t idx = (size_t)(node0 + grp * 4 + r) * CC + cb * 16 + col16;
      float ho = h[idx];
      h[idx] = (1.0f - z) * ng[cb][r] + z * ho;
    }
  }
}

// out[batch[n]] += h[n] . W_prop + b_prop   (wave per node)
__global__ __launch_bounds__(256) void prop_kernel(
    const float* __restrict__ h, const int* __restrict__ batch,
    const float* __restrict__ Wp, const float* __restrict__ bp,
    float* __restrict__ out)
{
  const int lane = threadIdx.x & 63;
  const int wid = (blockIdx.x * blockDim.x + threadIdx.x) >> 6;
  const int nw = (gridDim.x * blockDim.x) >> 6;
  for (int node = wid; node < NN; node += nw) {
    float v = h[(size_t)node * CC + lane] * Wp[lane]
            + h[(size_t)node * CC + 64 + lane] * Wp[64 + lane];
    #pragma unroll
    for (int off = 32; off > 0; off >>= 1) v += __shfl_down(v, off, 64);
    if (lane == 0) atomicAdd(&out[batch[node]], v + bp[0]);
  }
}

extern "C" void kernel_launch(void* const* d_in, const int* in_sizes, int n_in,
                              void* d_out, int out_size, void* d_ws, size_t ws_size,
                              hipStream_t stream)
{
  const float* x      = (const float*)d_in[0];
  const int*   eidx   = (const int*)d_in[1];
  const float* ew     = (const float*)d_in[2];
  const int*   batch  = (const int*)d_in[3];
  const float* W_emb  = (const float*)d_in[4];
  const float* b_emb  = (const float*)d_in[5];
  const float* W      = (const float*)d_in[6];
  const float* W_ih   = (const float*)d_in[7];
  const float* W_hh   = (const float*)d_in[8];
  const float* b_ih   = (const float*)d_in[9];
  const float* b_hh   = (const float*)d_in[10];
  const float* W_prop = (const float*)d_in[11];
  const float* b_prop = (const float*)d_in[12];
  float* out = (float*)d_out;

  // workspace layout (~117 MB)
  char* p = (char*)d_ws;
  float* h            = (float*)p;          p += (size_t)NN * CC * sizeof(float);  // 51.2 MB
  unsigned short* m   = (unsigned short*)p; p += (size_t)NN * CC * sizeof(short);  // 25.6 MB
  unsigned short* agg = (unsigned short*)p; p += (size_t)NN * CC * sizeof(short);  // 25.6 MB
  int* csr_src        = (int*)p;            p += (size_t)EE * sizeof(int);         // 6.4 MB
  float* csr_w        = (float*)p;          p += (size_t)EE * sizeof(float);       // 6.4 MB
  unsigned short* Wl_p  = (unsigned short*)p; p += (size_t)LL * 16384 * sizeof(short);
  unsigned short* Wih_p = (unsigned short*)p; p += (size_t)24 * 4 * 512 * sizeof(short);
  unsigned short* Whh_p = (unsigned short*)p; p += (size_t)24 * 4 * 512 * sizeof(short);
  int* deg     = (int*)p;                   p += (size_t)(NN + 256) * sizeof(int);
  int* row_ptr = (int*)p;                   p += (size_t)(NN + 256) * sizeof(int);
  int* cursor  = (int*)p;                   p += (size_t)(NN + 256) * sizeof(int);
  int* bsum    = (int*)p;                   p += 1024 * sizeof(int);

  const int NB_SCAN = (NN + 1023) / 1024;   // 98
  const int EB = (EE + 255) / 256;          // 6250
  const int MB = (NN + 63) / 64;            // 1563

  // ---- weight prepack (tiny, once per call) ----
  for (int l = 0; l < LL; ++l)
    pack_kernel<<<64, 256, 0, stream>>>(W + (size_t)l * CC * CC, Wl_p + (size_t)l * 16384, 4, 0, CC);
  pack_kernel<<<192, 256, 0, stream>>>(W_ih, Wih_p, 4, 1, CC);
  pack_kernel<<<192, 256, 0, stream>>>(W_hh, Whh_p, 4, 1, CC);

  // ---- CSR build ----
  hipMemsetAsync(deg, 0, (size_t)NN * sizeof(int), stream);
  hist_kernel<<<EB, 256, 0, stream>>>(eidx, deg);
  scan1_kernel<<<NB_SCAN, 256, 0, stream>>>(deg, bsum);
  scan2_kernel<<<1, 64, 0, stream>>>(bsum, NB_SCAN);
  scan3_kernel<<<NB_SCAN, 256, 0, stream>>>(deg, bsum, row_ptr, cursor);
  fill_kernel<<<EB, 256, 0, stream>>>(eidx, ew, cursor, csr_src, csr_w);

  // ---- main pipeline ----
  embed_kernel<<<NN, 128, 0, stream>>>(x, W_emb, b_emb, h);

  for (int l = 0; l < LL; ++l) {
    gemm_m_kernel<<<MB, 256, 0, stream>>>(h, Wl_p + (size_t)l * 16384, m);
    aggregate_kernel<<<(NN + 3) / 4, 256, 0, stream>>>(m, row_ptr, csr_src, csr_w, agg);
    gru_kernel<<<MB, 256, 0, stream>>>(agg, h, Wih_p, Whh_p, b_ih, b_hh);
  }

  hipMemsetAsync(d_out, 0, (size_t)GG * sizeof(float), stream);
  prop_kernel<<<2048, 256, 0, stream>>>(h, batch, W_prop, b_prop, out);
}

// Round 5
// 1127.418 us; speedup vs baseline: 5.7604x; 1.0602x over previous
//
#include <hip/hip_runtime.h>

#define NN 100000
#define CC 128
#define EE 1600000
#define GG 1024
#define LL 5

typedef __attribute__((ext_vector_type(8))) short bf16x8;
typedef __attribute__((ext_vector_type(4))) float f32x4;

__device__ __forceinline__ float sigmoidf_(float x) { return 1.0f / (1.0f + __expf(-x)); }
__device__ __forceinline__ float tanhf_(float x) {
  float xx = fminf(15.0f, fmaxf(-15.0f, x));
  float t = __expf(-2.0f * xx);
  return (1.0f - t) / (1.0f + t);
}
// f32 -> bf16 round-to-nearest-even
__device__ __forceinline__ unsigned short f2bf(float x) {
  unsigned int u = __float_as_uint(x);
  return (unsigned short)((u + 0x7fffu + ((u >> 16) & 1u)) >> 16);
}
__device__ __forceinline__ float bflo(unsigned int u) { return __uint_as_float(u << 16); }
__device__ __forceinline__ float bfhi(unsigned int u) { return __uint_as_float(u & 0xffff0000u); }

// ---------------- weight prepack ----------------
// Packed B-fragment layout: element (k, c) at t = ((cb*4+ks)*64 + l)*8 + i
// with k = ks*32 + 8*(l>>4) + i, c = cb*16 + (l&15).

// Whh: dst from W_hh^T (gh = h @ W_hh^T -> B[k][c] = W_hh[c][k])
__global__ __launch_bounds__(256) void pack_kernel(
    const float* __restrict__ src, unsigned short* __restrict__ dst)
{
  int t = blockIdx.x * 256 + threadIdx.x;           // 24*4*64*8 = 49152
  int i = t & 7, l = (t >> 3) & 63, q = t >> 9;
  int ks = q & 3, cb = q >> 2;
  int k = ks * 32 + 8 * (l >> 4) + i;
  int c = cb * 16 + (l & 15);
  dst[t] = f2bf(src[(size_t)c * CC + k]);
}

// Wfuse_l[k][c] = sum_j W_l[k][j] * W_ih[c][j]   (gi = aggP @ Wfuse)
__global__ __launch_bounds__(256) void fuse_pack_kernel(
    const float* __restrict__ Wl, const float* __restrict__ W_ih,
    unsigned short* __restrict__ dst)
{
  int t = blockIdx.x * 256 + threadIdx.x;           // 49152 per layer
  int i = t & 7, l = (t >> 3) & 63, q = t >> 9;
  int ks = q & 3, cb = q >> 2;
  int k = ks * 32 + 8 * (l >> 4) + i;
  int c = cb * 16 + (l & 15);
  const float* wl = Wl + (size_t)k * CC;
  const float* wi = W_ih + (size_t)c * CC;
  float acc = 0.f;
  #pragma unroll 8
  for (int j = 0; j < CC; ++j) acc = fmaf(wl[j], wi[j], acc);
  dst[t] = f2bf(acc);
}

// ---------------- CSR build (once per call) ----------------

__global__ __launch_bounds__(256) void hist_kernel(const int* __restrict__ eidx,
                                                   int* __restrict__ deg)
{
  int e = blockIdx.x * blockDim.x + threadIdx.x;
  if (e < EE) atomicAdd(&deg[eidx[EE + e]], 1);
}

__global__ __launch_bounds__(256) void scan1_kernel(const int* __restrict__ deg,
                                                    int* __restrict__ bsum)
{
  __shared__ int red[4];
  int base = blockIdx.x * 1024 + threadIdx.x * 4;
  int s = 0;
  #pragma unroll
  for (int i = 0; i < 4; ++i) { int idx = base + i; if (idx < NN) s += deg[idx]; }
  #pragma unroll
  for (int off = 32; off; off >>= 1) s += __shfl_down(s, off, 64);
  if ((threadIdx.x & 63) == 0) red[threadIdx.x >> 6] = s;
  __syncthreads();
  if (threadIdx.x == 0) bsum[blockIdx.x] = red[0] + red[1] + red[2] + red[3];
}

__global__ void scan2_kernel(int* __restrict__ bsum, int nb)
{
  if (threadIdx.x == 0 && blockIdx.x == 0) {
    int acc = 0;
    for (int i = 0; i < nb; ++i) { int v = bsum[i]; bsum[i] = acc; acc += v; }
  }
}

__global__ __launch_bounds__(256) void scan3_kernel(const int* __restrict__ deg,
                                                    const int* __restrict__ bsum,
                                                    int* __restrict__ row_ptr,
                                                    int* __restrict__ cursor)
{
  __shared__ int ts[256];
  const int tid = threadIdx.x;
  const int base = blockIdx.x * 1024 + tid * 4;
  int v[4]; int s = 0;
  #pragma unroll
  for (int i = 0; i < 4; ++i) { int idx = base + i; v[i] = (idx < NN) ? deg[idx] : 0; s += v[i]; }
  ts[tid] = s; __syncthreads();
  for (int off = 1; off < 256; off <<= 1) {
    int t = (tid >= off) ? ts[tid - off] : 0;
    __syncthreads();
    ts[tid] += t;
    __syncthreads();
  }
  int excl = bsum[blockIdx.x] + ts[tid] - s;
  #pragma unroll
  for (int i = 0; i < 4; ++i) {
    int idx = base + i;
    if (idx < NN) { row_ptr[idx] = excl; cursor[idx] = excl; excl += v[i]; }
  }
  if (blockIdx.x == 0 && tid == 0) row_ptr[NN] = EE;
}

// interleaved (src, weight) record: one 8B scattered store per edge
__global__ __launch_bounds__(256) void fill_kernel(const int* __restrict__ eidx,
                                                   const float* __restrict__ ew,
                                                   int* __restrict__ cursor,
                                                   int2* __restrict__ csr_sw)
{
  int e = blockIdx.x * blockDim.x + threadIdx.x;
  if (e < EE) {
    int d = eidx[EE + e];
    int p = atomicAdd(&cursor[d], 1);
    csr_sw[p] = make_int2(eidx[e], __float_as_int(ew[e]));
  }
}

// ---------------- main pipeline ----------------

// h0 = x @ W_emb + b_emb; writes f32 h and bf16 mirror
__global__ __launch_bounds__(128) void embed_kernel(
    const float* __restrict__ x, const float* __restrict__ W_emb,
    const float* __restrict__ b_emb, float* __restrict__ h,
    unsigned short* __restrict__ h_bf)
{
  const int node = blockIdx.x;
  const int c = threadIdx.x;
  float acc = b_emb[c];
  #pragma unroll
  for (int k = 0; k < 32; ++k)
    acc = fmaf(x[node * 32 + k], W_emb[k * CC + c], acc);
  h[(size_t)node * CC + c] = acc;
  h_bf[(size_t)node * CC + c] = f2bf(acc);
}

// aggP_bf[n] = bf16( sum_{e:dst=n} h_bf[src_e] * w_e )  — CSR gather.
// 4 quarters x 16 lanes; 8 edges in flight; shfl_xor combine.
__global__ __launch_bounds__(256) void aggregate_kernel(
    const unsigned short* __restrict__ h_bf, const int* __restrict__ row_ptr,
    const int2* __restrict__ csr_sw, unsigned short* __restrict__ agg_bf)
{
  const int lane = threadIdx.x & 63;
  const int node = (blockIdx.x * blockDim.x + threadIdx.x) >> 6;
  if (node >= NN) return;
  const int q = lane >> 4;          // quarter 0..3
  const int t = lane & 15;          // lane within quarter
  const int beg = row_ptr[node], end = row_ptr[node + 1];

  float acc[8] = {0.f, 0.f, 0.f, 0.f, 0.f, 0.f, 0.f, 0.f};
  const int last = end - 1;

  for (int j = beg; j < end; j += 8) {
    const int e0 = j + q, e1 = j + 4 + q;
    const int i0 = min(e0, last), i1 = min(e1, last);
    const int2 r0 = csr_sw[i0], r1 = csr_sw[i1];
    const int s0 = r0.x, s1 = r1.x;
    const float w0 = (e0 < end) ? __int_as_float(r0.y) : 0.0f;
    const float w1 = (e1 < end) ? __int_as_float(r1.y) : 0.0f;
    const uint4 u0 = *(const uint4*)(h_bf + (size_t)s0 * CC + t * 8);
    const uint4 u1 = *(const uint4*)(h_bf + (size_t)s1 * CC + t * 8);
    acc[0] = fmaf(bflo(u0.x), w0, acc[0]); acc[1] = fmaf(bfhi(u0.x), w0, acc[1]);
    acc[2] = fmaf(bflo(u0.y), w0, acc[2]); acc[3] = fmaf(bfhi(u0.y), w0, acc[3]);
    acc[4] = fmaf(bflo(u0.z), w0, acc[4]); acc[5] = fmaf(bfhi(u0.z), w0, acc[5]);
    acc[6] = fmaf(bflo(u0.w), w0, acc[6]); acc[7] = fmaf(bfhi(u0.w), w0, acc[7]);
    acc[0] = fmaf(bflo(u1.x), w1, acc[0]); acc[1] = fmaf(bfhi(u1.x), w1, acc[1]);
    acc[2] = fmaf(bflo(u1.y), w1, acc[2]); acc[3] = fmaf(bfhi(u1.y), w1, acc[3]);
    acc[4] = fmaf(bflo(u1.z), w1, acc[4]); acc[5] = fmaf(bfhi(u1.z), w1, acc[5]);
    acc[6] = fmaf(bflo(u1.w), w1, acc[6]); acc[7] = fmaf(bfhi(u1.w), w1, acc[7]);
  }

  #pragma unroll
  for (int i = 0; i < 8; ++i) {
    acc[i] += __shfl_xor(acc[i], 16, 64);
    acc[i] += __shfl_xor(acc[i], 32, 64);
  }

  if (q == 0) {
    uint4 o;
    o.x = (unsigned)f2bf(acc[0]) | ((unsigned)f2bf(acc[1]) << 16);
    o.y = (unsigned)f2bf(acc[2]) | ((unsigned)f2bf(acc[3]) << 16);
    o.z = (unsigned)f2bf(acc[4]) | ((unsigned)f2bf(acc[5]) << 16);
    o.w = (unsigned)f2bf(acc[6]) | ((unsigned)f2bf(acc[7]) << 16);
    *(uint4*)(agg_bf + (size_t)node * CC + t * 8) = o;
  }
}

// fused GRU via MFMA: h = GRU(aggP @ Wfuse, h).  gi = aggP @ Wfuse (+b_ih),
// gh = h @ W_hh^T (+b_hh).  cols: r 0..127 | z 128..255 | n 256..383.
__global__ __launch_bounds__(256) void gru_kernel(
    const unsigned short* __restrict__ agg_bf, float* __restrict__ h,
    unsigned short* __restrict__ h_bf,
    const unsigned short* __restrict__ Wfuse_p, const unsigned short* __restrict__ Whh_p,
    const float* __restrict__ b_ih, const float* __restrict__ b_hh)
{
  const int lane = threadIdx.x & 63;
  const int wave = threadIdx.x >> 6;
  const int node0 = blockIdx.x * 64 + wave * 16;
  if (node0 >= NN) return;
  const int col16 = lane & 15, grp = lane >> 4;

  bf16x8 aA[4], aH[4];
  {
    const unsigned short* arow = agg_bf + (size_t)(node0 + col16) * CC + grp * 8;
    const unsigned short* hrow = h_bf + (size_t)(node0 + col16) * CC + grp * 8;
    #pragma unroll
    for (int ks = 0; ks < 4; ++ks) {
      aA[ks] = *(const bf16x8*)(arow + ks * 32);
      aH[ks] = *(const bf16x8*)(hrow + ks * 32);
    }
  }

  float rg[8][4], ng[8][4];

  // ---- r gate (cb 0..7) ----
  #pragma unroll
  for (int cb = 0; cb < 8; ++cb) {
    f32x4 ai = {0.f, 0.f, 0.f, 0.f}, ah = {0.f, 0.f, 0.f, 0.f};
    #pragma unroll
    for (int ks = 0; ks < 4; ++ks) {
      bf16x8 bi = *(const bf16x8*)(Wfuse_p + (size_t)((cb * 4 + ks) * 64 + lane) * 8);
      bf16x8 bh = *(const bf16x8*)(Whh_p + (size_t)((cb * 4 + ks) * 64 + lane) * 8);
      ai = __builtin_amdgcn_mfma_f32_16x16x32_bf16(aA[ks], bi, ai, 0, 0, 0);
      ah = __builtin_amdgcn_mfma_f32_16x16x32_bf16(aH[ks], bh, ah, 0, 0, 0);
    }
    const int o = cb * 16 + col16;
    const float bi_ = b_ih[o], bh_ = b_hh[o];
    #pragma unroll
    for (int r = 0; r < 4; ++r)
      rg[cb][r] = sigmoidf_(ai[r] + ah[r] + bi_ + bh_);
  }

  // ---- n gate (cb 16..23): n = tanh(i_n + b_in + r*(h_n + b_hn)) ----
  #pragma unroll
  for (int cb = 0; cb < 8; ++cb) {
    f32x4 ai = {0.f, 0.f, 0.f, 0.f}, ah = {0.f, 0.f, 0.f, 0.f};
    #pragma unroll
    for (int ks = 0; ks < 4; ++ks) {
      bf16x8 bi = *(const bf16x8*)(Wfuse_p + (size_t)(((16 + cb) * 4 + ks) * 64 + lane) * 8);
      bf16x8 bh = *(const bf16x8*)(Whh_p + (size_t)(((16 + cb) * 4 + ks) * 64 + lane) * 8);
      ai = __builtin_amdgcn_mfma_f32_16x16x32_bf16(aA[ks], bi, ai, 0, 0, 0);
      ah = __builtin_amdgcn_mfma_f32_16x16x32_bf16(aH[ks], bh, ah, 0, 0, 0);
    }
    const int o = 256 + cb * 16 + col16;
    const float bi_ = b_ih[o], bh_ = b_hh[o];
    #pragma unroll
    for (int r = 0; r < 4; ++r)
      ng[cb][r] = tanhf_(ai[r] + bi_ + rg[cb][r] * (ah[r] + bh_));
  }

  // ---- z gate (cb 8..15) + blend + store f32 h and bf16 mirror ----
  #pragma unroll
  for (int cb = 0; cb < 8; ++cb) {
    f32x4 ai = {0.f, 0.f, 0.f, 0.f}, ah = {0.f, 0.f, 0.f, 0.f};
    #pragma unroll
    for (int ks = 0; ks < 4; ++ks) {
      bf16x8 bi = *(const bf16x8*)(Wfuse_p + (size_t)(((8 + cb) * 4 + ks) * 64 + lane) * 8);
      bf16x8 bh = *(const bf16x8*)(Whh_p + (size_t)(((8 + cb) * 4 + ks) * 64 + lane) * 8);
      ai = __builtin_amdgcn_mfma_f32_16x16x32_bf16(aA[ks], bi, ai, 0, 0, 0);
      ah = __builtin_amdgcn_mfma_f32_16x16x32_bf16(aH[ks], bh, ah, 0, 0, 0);
    }
    const int o = 128 + cb * 16 + col16;
    const float bi_ = b_ih[o], bh_ = b_hh[o];
    #pragma unroll
    for (int r = 0; r < 4; ++r) {
      float z = sigmoidf_(ai[r] + ah[r] + bi_ + bh_);
      size_t idx = (size_t)(node0 + grp * 4 + r) * CC + cb * 16 + col16;
      float hn = (1.0f - z) * ng[cb][r] + z * h[idx];
      h[idx] = hn;
      h_bf[idx] = f2bf(hn);
    }
  }
}

// out[batch[n]] += h[n] . W_prop + b_prop   (wave per node)
__global__ __launch_bounds__(256) void prop_kernel(
    const float* __restrict__ h, const int* __restrict__ batch,
    const float* __restrict__ Wp, const float* __restrict__ bp,
    float* __restrict__ out)
{
  const int lane = threadIdx.x & 63;
  const int wid = (blockIdx.x * blockDim.x + threadIdx.x) >> 6;
  const int nw = (gridDim.x * blockDim.x) >> 6;
  for (int node = wid; node < NN; node += nw) {
    float v = h[(size_t)node * CC + lane] * Wp[lane]
            + h[(size_t)node * CC + 64 + lane] * Wp[64 + lane];
    #pragma unroll
    for (int off = 32; off > 0; off >>= 1) v += __shfl_down(v, off, 64);
    if (lane == 0) atomicAdd(&out[batch[node]], v + bp[0]);
  }
}

extern "C" void kernel_launch(void* const* d_in, const int* in_sizes, int n_in,
                              void* d_out, int out_size, void* d_ws, size_t ws_size,
                              hipStream_t stream)
{
  const float* x      = (const float*)d_in[0];
  const int*   eidx   = (const int*)d_in[1];
  const float* ew     = (const float*)d_in[2];
  const int*   batch  = (const int*)d_in[3];
  const float* W_emb  = (const float*)d_in[4];
  const float* b_emb  = (const float*)d_in[5];
  const float* W      = (const float*)d_in[6];
  const float* W_ih   = (const float*)d_in[7];
  const float* W_hh   = (const float*)d_in[8];
  const float* b_ih   = (const float*)d_in[9];
  const float* b_hh   = (const float*)d_in[10];
  const float* W_prop = (const float*)d_in[11];
  const float* b_prop = (const float*)d_in[12];
  float* out = (float*)d_out;

  // workspace layout (~116 MB)
  char* p = (char*)d_ws;
  float* h              = (float*)p;          p += (size_t)NN * CC * sizeof(float);  // 51.2 MB
  unsigned short* h_bf  = (unsigned short*)p; p += (size_t)NN * CC * sizeof(short);  // 25.6 MB
  unsigned short* agg   = (unsigned short*)p; p += (size_t)NN * CC * sizeof(short);  // 25.6 MB
  int2* csr_sw          = (int2*)p;           p += (size_t)EE * sizeof(int2);        // 12.8 MB
  unsigned short* Wfuse_p = (unsigned short*)p; p += (size_t)LL * 49152 * sizeof(short);
  unsigned short* Whh_p = (unsigned short*)p; p += (size_t)49152 * sizeof(short);
  int* deg     = (int*)p;                     p += (size_t)(NN + 256) * sizeof(int);
  int* row_ptr = (int*)p;                     p += (size_t)(NN + 256) * sizeof(int);
  int* cursor  = (int*)p;                     p += (size_t)(NN + 256) * sizeof(int);
  int* bsum    = (int*)p;                     p += 1024 * sizeof(int);

  const int NB_SCAN = (NN + 1023) / 1024;   // 98
  const int EB = (EE + 255) / 256;          // 6250
  const int MB = (NN + 63) / 64;            // 1563

  // ---- weight prepack (once per call) ----
  pack_kernel<<<192, 256, 0, stream>>>(W_hh, Whh_p);
  for (int l = 0; l < LL; ++l)
    fuse_pack_kernel<<<192, 256, 0, stream>>>(W + (size_t)l * CC * CC, W_ih,
                                              Wfuse_p + (size_t)l * 49152);

  // ---- CSR build ----
  hipMemsetAsync(deg, 0, (size_t)NN * sizeof(int), stream);
  hist_kernel<<<EB, 256, 0, stream>>>(eidx, deg);
  scan1_kernel<<<NB_SCAN, 256, 0, stream>>>(deg, bsum);
  scan2_kernel<<<1, 64, 0, stream>>>(bsum, NB_SCAN);
  scan3_kernel<<<NB_SCAN, 256, 0, stream>>>(deg, bsum, row_ptr, cursor);
  fill_kernel<<<EB, 256, 0, stream>>>(eidx, ew, cursor, csr_sw);

  // ---- main pipeline ----
  embed_kernel<<<NN, 128, 0, stream>>>(x, W_emb, b_emb, h, h_bf);

  for (int l = 0; l < LL; ++l) {
    aggregate_kernel<<<(NN + 3) / 4, 256, 0, stream>>>(h_bf, row_ptr, csr_sw, agg);
    gru_kernel<<<MB, 256, 0, stream>>>(agg, h, h_bf,
                                       Wfuse_p + (size_t)l * 49152, Whh_p, b_ih, b_hh);
  }

  hipMemsetAsync(d_out, 0, (size_t)GG * sizeof(float), stream);
  prop_kernel<<<2048, 256, 0, stream>>>(h, batch, W_prop, b_prop, out);
}